// Round 8
// baseline (491.361 us; speedup 1.0000x reference)
//
#include <hip/hip_runtime.h>

#define PLANE 1042441      // 1021*1021
#define S1 255             // h1 even-grid / h3 core spatial
#define S2 253             // h2 spatial
#define S1S1 65025
#define S2S2 64009
#define NOUT 66716224      // 8*8*1021*1021

typedef float v4f __attribute__((ext_vector_type(4)));  // native vec for nontemporal builtins

// ws layout (floats): h1e[4161600] | h2[8193152] | h3c[4161600] | R[32] | WT[768]

// R[co*4+pc] = sum_ci relu(b3[ci]) * sum_{off-core taps for pc} w4[co][ci][jy][jx]
// WT[(co*8+ci)*12] = packed w4: [w00,w02,w20,w22, w01,w21,w10,w12, w11,0,0,0]
__global__ void k_setup(const float* __restrict__ w4, const float* __restrict__ b3_,
                        float* __restrict__ R, float* __restrict__ WT) {
  int t = threadIdx.x;
  if (t < 32) {
    int co = t >> 2, pc = t & 3;
    float s = 0.f;
    for (int ci = 0; ci < 8; ++ci) {
      float r3 = fmaxf(b3_[ci], 0.f);
      float wsum = 0.f;
      for (int jy = 0; jy < 3; ++jy)
        for (int jx = 0; jx < 3; ++jx) {
          bool cy = (pc & 2) ? (jy == 1) : (jy != 1);
          bool cx = (pc & 1) ? (jx == 1) : (jx != 1);
          if (!(cy && cx)) wsum += w4[(co * 8 + ci) * 9 + jy * 3 + jx];
        }
      s += r3 * wsum;
    }
    R[t] = s;
  }
  {
    int co = t >> 3, ci = t & 7;
    const float* w = w4 + (co * 8 + ci) * 9;
    float* d = WT + (co * 8 + ci) * 12;
    d[0] = w[0]; d[1] = w[2]; d[2] = w[6]; d[3] = w[8];
    d[4] = w[1]; d[5] = w[7]; d[6] = w[3]; d[7] = w[5];
    d[8] = w[4]; d[9] = 0.f; d[10] = 0.f; d[11] = 0.f;
  }
}

// conv1: single pass over x. Each thread: 4 outputs x ALL 8 co (32 acc).
__global__ __launch_bounds__(256) void k_conv1(const float* __restrict__ x,
    const float* __restrict__ w1, const float* __restrict__ b1_, float* __restrict__ h1e) {
  int tx = threadIdx.x;                      // 0..63
  int t0 = tx * 4;                           // output col base, 0..252
  int m = blockIdx.y * 4 + threadIdx.y;      // output row
  if (m >= S1) return;
  int n = blockIdx.z;

  float acc[8][4];
#pragma unroll
  for (int cc = 0; cc < 8; ++cc) {
    float b = b1_[cc];
#pragma unroll
    for (int p = 0; p < 4; ++p) acc[cc][p] = b;
  }

  const float* xn = x + (size_t)n * 3 * PLANE;
  int b0 = 16 * tx;                          // x col base, <= 1008
  int o7 = b0 + 14 <= 1020 ? b0 + 14 : 1020;
  int o8 = b0 + 16 <= 1020 ? b0 + 16 : 1020;

#pragma unroll
  for (int ci = 0; ci < 3; ++ci) {
#pragma unroll
    for (int ky = 0; ky < 3; ++ky) {
      const float* xr = xn + ci * PLANE + (size_t)(4 * m + 2 * ky) * 1021u;
      float4 qa = *(const float4*)(xr + b0);
      float4 qb = *(const float4*)(xr + b0 + 4);
      float4 qc = *(const float4*)(xr + b0 + 8);
      float v[9];
      v[0] = qa.x; v[1] = qa.z; v[2] = qb.x; v[3] = qb.z;
      v[4] = qc.x; v[5] = qc.z;
      v[6] = xr[b0 + 12];
      v[7] = xr[o7]; v[8] = xr[o8];
#pragma unroll
      for (int cc = 0; cc < 8; ++cc) {
        const float* w = w1 + cc * 27 + ci * 9 + ky * 3;
        float w0 = w[0], w1v = w[1], w2v = w[2];
#pragma unroll
        for (int p = 0; p < 4; ++p)
          acc[cc][p] = fmaf(v[2 * p], w0, fmaf(v[2 * p + 1], w1v, fmaf(v[2 * p + 2], w2v, acc[cc][p])));
      }
    }
  }

#pragma unroll
  for (int cc = 0; cc < 8; ++cc) {
    float* op = h1e + ((size_t)(n * 8 + cc) * S1 + m) * S1 + t0;
    if (t0 + 3 < S1) {
      *(float4*)op = make_float4(fmaxf(acc[cc][0], 0.f), fmaxf(acc[cc][1], 0.f),
                                 fmaxf(acc[cc][2], 0.f), fmaxf(acc[cc][3], 0.f));
    } else {
#pragma unroll
      for (int p = 0; p < 4; ++p)
        if (t0 + p < S1) op[p] = fmaxf(acc[cc][p], 0.f);
    }
  }
}

// h2: 4 pixels x 8 co per thread. float4 row-segment loads.
__global__ __launch_bounds__(256) void k_conv2(const float* __restrict__ h1e,
    const float* __restrict__ w2, const float* __restrict__ b2_, float* __restrict__ h2) {
  int v0 = threadIdx.x * 4;                  // 0..252
  int u = blockIdx.y * 4 + threadIdx.y;
  int zb = blockIdx.z;                       // n*2 + g
  int n = zb >> 1, cog = (zb & 1) * 8;
  if (u >= S2) return;
  float acc[8][4];
#pragma unroll
  for (int cc = 0; cc < 8; ++cc) {
    float b = b2_[cog + cc];
#pragma unroll
    for (int p = 0; p < 4; ++p) acc[cc][p] = b;
  }
  const float* hn = h1e + (size_t)n * 8 * S1S1;
  for (int ci = 0; ci < 8; ++ci) {
    const float* hc = hn + ci * S1S1;
#pragma unroll
    for (int ky = 0; ky < 3; ++ky) {
      const float* hr = hc + (u + ky) * S1 + v0;
      float4 r4 = *(const float4*)hr;
      float rr[6] = {r4.x, r4.y, r4.z, r4.w, hr[4], hr[5]};
#pragma unroll
      for (int cc = 0; cc < 8; ++cc) {
        const float* w = w2 + (cog + cc) * 72 + ci * 9 + ky * 3;
        float w0 = w[0], w1 = w[1], w2v = w[2];
#pragma unroll
        for (int p = 0; p < 4; ++p)
          acc[cc][p] = fmaf(rr[p], w0, fmaf(rr[p + 1], w1, fmaf(rr[p + 2], w2v, acc[cc][p])));
      }
    }
  }
#pragma unroll
  for (int cc = 0; cc < 8; ++cc) {
    float* op = h2 + ((size_t)(n * 16 + cog + cc) * S2 + u) * S2 + v0;
    if (v0 + 3 < S2) {
      *(float4*)op = make_float4(fmaxf(acc[cc][0], 0.f), fmaxf(acc[cc][1], 0.f),
                                 fmaxf(acc[cc][2], 0.f), fmaxf(acc[cc][3], 0.f));
    } else {
#pragma unroll
      for (int p = 0; p < 4; ++p)
        if (v0 + p < S2) op[p] = fmaxf(acc[cc][p], 0.f);
    }
  }
}

// h3core: 4 pixels x 8 co per thread. float4 row-segment loads.
__global__ __launch_bounds__(256) void k_deconv3(const float* __restrict__ h2,
    const float* __restrict__ w3, const float* __restrict__ b3_, float* __restrict__ h3c) {
  int r0 = threadIdx.x * 4;                  // 0..252
  int q = blockIdx.y * 4 + threadIdx.y;
  int n = blockIdx.z;
  if (q >= S1) return;
  float acc[8][4];
#pragma unroll
  for (int cc = 0; cc < 8; ++cc) {
    float b = b3_[cc];
#pragma unroll
    for (int p = 0; p < 4; ++p) acc[cc][p] = b;
  }
  const float* hn = h2 + (size_t)n * 16 * S2S2;
  bool inner = (r0 >= 4 && r0 <= 248);
  for (int ci = 0; ci < 16; ++ci) {
    const float* hc = hn + ci * S2S2;
#pragma unroll
    for (int jy = 0; jy < 3; ++jy) {
      int a = q - jy;
      if ((unsigned)a > 252u) continue;
      const float* hr = hc + a * S2 + (r0 - 2);
      float rr[6];
      if (inner) {
        float4 r4 = *(const float4*)hr;
        rr[0] = r4.x; rr[1] = r4.y; rr[2] = r4.z; rr[3] = r4.w;
        rr[4] = hr[4]; rr[5] = hr[5];
      } else {
#pragma unroll
        for (int q2 = 0; q2 < 6; ++q2) {
          int col = r0 - 2 + q2;
          rr[q2] = ((unsigned)col <= 252u) ? hr[q2] : 0.f;
        }
      }
#pragma unroll
      for (int cc = 0; cc < 8; ++cc) {
        const float* w = w3 + (cc * 16 + ci) * 9 + jy * 3;
        float w0 = w[0], w1 = w[1], w2v = w[2];
#pragma unroll
        for (int p = 0; p < 4; ++p)
          acc[cc][p] = fmaf(rr[p + 2], w0, fmaf(rr[p + 1], w1, fmaf(rr[p], w2v, acc[cc][p])));
      }
    }
  }
#pragma unroll
  for (int cc = 0; cc < 8; ++cc) {
    float* op = h3c + ((size_t)(n * 8 + cc) * S1 + q) * S1 + r0;
    if (r0 + 3 < S1) {
      *(float4*)op = make_float4(fmaxf(acc[cc][0], 0.f), fmaxf(acc[cc][1], 0.f),
                                 fmaxf(acc[cc][2], 0.f), fmaxf(acc[cc][3], 0.f));
    } else {
#pragma unroll
      for (int p = 0; p < 4; ++p)
        if (r0 + p < S1) op[p] = fmaxf(acc[cc][p], 0.f);
    }
  }
}

// General (border) per-element output value.
__device__ __forceinline__ float general_val(unsigned idx, const float* __restrict__ h3c,
    const float* __restrict__ w4, const float* __restrict__ b4_, const float* __restrict__ b3_) {
  unsigned z = idx / PLANE;
  unsigned rem = idx - z * PLANE;
  unsigned y = rem / 1021u;
  unsigned x = rem - y * 1021u;
  int co = z & 7;
  float acc = b4_[co];
  if ((y | x) & 1u) return acc;
  int py = y >> 1, px = x >> 1;
  const float* hn = h3c + (size_t)(z >> 3) * 8 * S1S1;
  const float* wp = w4 + co * 72;
  for (int ci = 0; ci < 8; ++ci) {
    float r3 = fmaxf(b3_[ci], 0.f);
    const float* hcc = hn + ci * S1S1;
#pragma unroll
    for (int jy = 0; jy < 3; ++jy) {
      int a = py - jy;
#pragma unroll
      for (int jx = 0; jx < 3; ++jx) {
        int b = px - jx;
        float h;
        if ((unsigned)a > 508u || (unsigned)b > 508u) h = 0.f;
        else if (((a | b) & 1) == 0) h = hcc[(a >> 1) * S1 + (b >> 1)];
        else h = r3;
        acc = fmaf(h, wp[ci * 9 + jy * 3 + jx], acc);
      }
    }
  }
  return acc;
}

// Pure-constant fill of all odd rows. One block per (z, odd row).
__global__ __launch_bounds__(256) void k_fill_odd(const float* __restrict__ b4_,
                                                  float* __restrict__ out) {
  int t = threadIdx.x;
  int yo = 1 + blockIdx.x * 2;               // 1..1019
  int z = blockIdx.y;
  float b4f = b4_[z & 7];
  float* row = out + (size_t)z * PLANE + (size_t)yo * 1021u;
  int al = (4 - ((z + yo) & 3)) & 3;         // head floats to reach 16B alignment
  int f4n = (1021 - al) >> 2;                // 254 or 255 aligned float4s
  if (t < f4n) {
    v4f v = {b4f, b4f, b4f, b4f};
    __builtin_nontemporal_store(v, (v4f*)(row + al + 4 * t));
  } else if (t == 255) {
    for (int i = 0; i < al; ++i) row[i] = b4f;
    for (int i = al + 4 * f4n; i < 1021; ++i) row[i] = b4f;
  }
}

// Interior even rows (ye 4..1016), aligned nontemporal v4f stores.
// Thread t in [1,252] covers cols c0=al+4t .. c0+3 (even-px range [2,507] -> R exact).
// pxa may be EVEN or ODD here (al varies) -> keep the pxodd-dependent operand select.
__global__ __launch_bounds__(256) void k_out_even(const float* __restrict__ h3c,
    const float* __restrict__ b4_, const float* __restrict__ R,
    const float* __restrict__ WT, float* __restrict__ out) {
  int t = threadIdx.x;
  if (t == 0 || t > 252) return;
  int ye = 4 + blockIdx.x * 2;               // 4..1016
  int z = blockIdx.y;                        // n*8+co
  int co = z & 7;
  float b4f = b4_[co];
  float* orow = out + (size_t)z * PLANE + (size_t)ye * 1021u;
  int al = (4 - ((z + ye) & 3)) & 3;         // block-uniform alignment
  int c0 = al + 4 * t;                       // cols c0..c0+3, within [4, 1014]
  unsigned py = (unsigned)ye >> 1;           // 2..508
  unsigned e0 = c0 + (c0 & 1);               // first even col in chunk
  unsigned pxa = e0 >> 1;                    // 2..506
  unsigned col0 = (pxa - 1u) >> 1;           // same for pxa and pxa+1 parity partner
  unsigned pxodd = pxa & 1u;
  const float* hn = h3c + (size_t)(z >> 3) * 8 * S1S1;
  const float* wt = WT + co * 96;
  float vE = 0.f, vO = 0.f, rE, rO;
  if ((py & 1u) == 0) {
    unsigned i = py >> 1;                    // rows i-1, i of h3c
    const float* hp = hn + (i - 1) * S1 + col0;
#pragma unroll
    for (int ci = 0; ci < 8; ++ci) {
      const float* p = hp + ci * S1S1;
      float m00 = p[0], m01 = p[1], m10 = p[S1], m11 = p[S1 + 1];
      float4 A = *(const float4*)(wt + ci * 12);
      float4 B = *(const float4*)(wt + ci * 12 + 4);
      vE = fmaf(m11, A.x, fmaf(m10, A.y, fmaf(m01, A.z, fmaf(m00, A.w, vE))));
      float t1 = pxodd ? m10 : m11;
      float t0 = pxodd ? m00 : m01;
      vO = fmaf(t1, B.x, fmaf(t0, B.y, vO));
    }
    rE = b4f + R[co * 4 + 0] + vE;
    rO = b4f + R[co * 4 + 1] + vO;
  } else {
    unsigned a = py >> 1;                    // single row a of h3c
    const float* hp = hn + a * S1 + col0;
#pragma unroll
    for (int ci = 0; ci < 8; ++ci) {
      const float* p = hp + ci * S1S1;
      float n0 = p[0], n1 = p[1];
      float4 B = *(const float4*)(wt + ci * 12 + 4);
      float w11 = wt[ci * 12 + 8];
      vE = fmaf(n1, B.z, fmaf(n0, B.w, vE));
      vO = fmaf(pxodd ? n0 : n1, w11, vO);
    }
    rE = b4f + R[co * 4 + 2] + vE;
    rO = b4f + R[co * 4 + 3] + vO;
  }
  float va = pxodd ? rO : rE;                // value at e0 (px = pxa)
  float vb = pxodd ? rE : rO;                // value at e0+2 (px = pxa+1)
  v4f v;
  if (c0 & 1) { v.x = b4f; v.y = va; v.z = b4f; v.w = vb; }
  else        { v.x = va; v.y = b4f; v.z = vb; v.w = b4f; }
  __builtin_nontemporal_store(v, (v4f*)(orow + c0));
}

// Border kernel: even-row x-borders (x in {0..6} u {1012..1020}, ye=4..1016: 507 rows)
// and the 4 even border rows (y in {0,2,1018,1020}) in full. Overlap with k_out_even
// is benign (serialized kernels, both compute correct values).
__global__ __launch_bounds__(256) void k_out_border(const float* __restrict__ h3c,
    const float* __restrict__ w4, const float* __restrict__ b4_,
    const float* __restrict__ b3_, float* __restrict__ out) {
  int z = blockIdx.y;
  unsigned y, x;
  if (blockIdx.x < 32) {                     // x-border: 507*16 = 8112 elements
    unsigned e = blockIdx.x * 256 + threadIdx.x;
    if (e >= 507u * 16u) return;
    unsigned r = e >> 4, c = e & 15u;
    y = 4u + 2u * r;
    x = (c < 7u) ? c : (1005u + c);          // c=7..15 -> 1012..1020
  } else {                                   // y-border rows: 4*1021 = 4084 elements
    unsigned e2 = (blockIdx.x - 32) * 256 + threadIdx.x;
    if (e2 >= 4u * 1021u) return;
    unsigned rr = e2 / 1021u;
    y = (rr < 2u) ? 2u * rr : (1014u + 2u * rr);   // 0,2,1018,1020
    x = e2 - rr * 1021u;
  }
  unsigned idx = (unsigned)z * PLANE + y * 1021u + x;
  out[idx] = general_val(idx, h3c, w4, b4_, b3_);
}

extern "C" void kernel_launch(void* const* d_in, const int* in_sizes, int n_in,
                              void* d_out, int out_size, void* d_ws, size_t ws_size,
                              hipStream_t stream) {
  const float* x   = (const float*)d_in[0];
  const float* w1  = (const float*)d_in[1];
  const float* b1_ = (const float*)d_in[2];
  const float* w2  = (const float*)d_in[3];
  const float* b2_ = (const float*)d_in[4];
  const float* w3  = (const float*)d_in[5];
  const float* b3_ = (const float*)d_in[6];
  const float* w4  = (const float*)d_in[7];
  const float* b4_ = (const float*)d_in[8];
  float* out = (float*)d_out;

  float* h1e = (float*)d_ws;
  float* h2  = h1e + (size_t)8 * 8 * S1S1;
  float* h3c = h2 + (size_t)8 * 16 * S2S2;
  float* R   = h3c + (size_t)8 * 8 * S1S1;
  float* WT  = R + 32;

  k_setup<<<1, 64, 0, stream>>>(w4, b3_, R, WT);
  k_conv1<<<dim3(1, 64, 8), dim3(64, 4), 0, stream>>>(x, w1, b1_, h1e);
  k_conv2<<<dim3(1, 64, 16), dim3(64, 4), 0, stream>>>(h1e, w2, b2_, h2);
  k_deconv3<<<dim3(1, 64, 8), dim3(64, 4), 0, stream>>>(h2, w3, b3_, h3c);
  k_fill_odd<<<dim3(510, 64), 256, 0, stream>>>(b4_, out);
  k_out_even<<<dim3(507, 64), 256, 0, stream>>>(h3c, b4_, R, WT, out);
  k_out_border<<<dim3(48, 64), 256, 0, stream>>>(h3c, w4, b4_, b3_, out);
}

// Round 9
// 451.792 us; speedup vs baseline: 1.0876x; 1.0876x over previous
//
#include <hip/hip_runtime.h>

#define PLANE 1042441      // 1021*1021
#define S1 255             // h1 even-grid / h3 core spatial
#define S2 253             // h2 spatial
#define S1S1 65025
#define S2S2 64009
#define NOUT 66716224      // 8*8*1021*1021

// ws layout (floats): h1e[4161600] | h2[8193152] | h3c[4161600] | R[32] | WT[768]

// R[co*4+pc] = sum_ci relu(b3[ci]) * sum_{off-core taps for pc} w4[co][ci][jy][jx]
// WT[(co*8+ci)*12] = packed w4: [w00,w02,w20,w22, w01,w21,w10,w12, w11,0,0,0]
__global__ void k_setup(const float* __restrict__ w4, const float* __restrict__ b3_,
                        float* __restrict__ R, float* __restrict__ WT) {
  int t = threadIdx.x;
  if (t < 32) {
    int co = t >> 2, pc = t & 3;
    float s = 0.f;
    for (int ci = 0; ci < 8; ++ci) {
      float r3 = fmaxf(b3_[ci], 0.f);
      float wsum = 0.f;
      for (int jy = 0; jy < 3; ++jy)
        for (int jx = 0; jx < 3; ++jx) {
          bool cy = (pc & 2) ? (jy == 1) : (jy != 1);
          bool cx = (pc & 1) ? (jx == 1) : (jx != 1);
          if (!(cy && cx)) wsum += w4[(co * 8 + ci) * 9 + jy * 3 + jx];
        }
      s += r3 * wsum;
    }
    R[t] = s;
  }
  {
    int co = t >> 3, ci = t & 7;
    const float* w = w4 + (co * 8 + ci) * 9;
    float* d = WT + (co * 8 + ci) * 12;
    d[0] = w[0]; d[1] = w[2]; d[2] = w[6]; d[3] = w[8];
    d[4] = w[1]; d[5] = w[7]; d[6] = w[3]; d[7] = w[5];
    d[8] = w[4]; d[9] = 0.f; d[10] = 0.f; d[11] = 0.f;
  }
}

// conv1: single pass over x. Each thread: 4 outputs x ALL 8 co (32 acc).
__global__ __launch_bounds__(256) void k_conv1(const float* __restrict__ x,
    const float* __restrict__ w1, const float* __restrict__ b1_, float* __restrict__ h1e) {
  int tx = threadIdx.x;                      // 0..63
  int t0 = tx * 4;                           // output col base, 0..252
  int m = blockIdx.y * 4 + threadIdx.y;      // output row
  if (m >= S1) return;
  int n = blockIdx.z;

  float acc[8][4];
#pragma unroll
  for (int cc = 0; cc < 8; ++cc) {
    float b = b1_[cc];
#pragma unroll
    for (int p = 0; p < 4; ++p) acc[cc][p] = b;
  }

  const float* xn = x + (size_t)n * 3 * PLANE;
  int b0 = 16 * tx;                          // x col base, <= 1008
  int o7 = b0 + 14 <= 1020 ? b0 + 14 : 1020;
  int o8 = b0 + 16 <= 1020 ? b0 + 16 : 1020;

#pragma unroll
  for (int ci = 0; ci < 3; ++ci) {
#pragma unroll
    for (int ky = 0; ky < 3; ++ky) {
      const float* xr = xn + ci * PLANE + (size_t)(4 * m + 2 * ky) * 1021u;
      float4 qa = *(const float4*)(xr + b0);
      float4 qb = *(const float4*)(xr + b0 + 4);
      float4 qc = *(const float4*)(xr + b0 + 8);
      float v[9];
      v[0] = qa.x; v[1] = qa.z; v[2] = qb.x; v[3] = qb.z;
      v[4] = qc.x; v[5] = qc.z;
      v[6] = xr[b0 + 12];
      v[7] = xr[o7]; v[8] = xr[o8];
#pragma unroll
      for (int cc = 0; cc < 8; ++cc) {
        const float* w = w1 + cc * 27 + ci * 9 + ky * 3;
        float w0 = w[0], w1v = w[1], w2v = w[2];
#pragma unroll
        for (int p = 0; p < 4; ++p)
          acc[cc][p] = fmaf(v[2 * p], w0, fmaf(v[2 * p + 1], w1v, fmaf(v[2 * p + 2], w2v, acc[cc][p])));
      }
    }
  }

#pragma unroll
  for (int cc = 0; cc < 8; ++cc) {
    float* op = h1e + ((size_t)(n * 8 + cc) * S1 + m) * S1 + t0;
    if (t0 + 3 < S1) {
      *(float4*)op = make_float4(fmaxf(acc[cc][0], 0.f), fmaxf(acc[cc][1], 0.f),
                                 fmaxf(acc[cc][2], 0.f), fmaxf(acc[cc][3], 0.f));
    } else {
#pragma unroll
      for (int p = 0; p < 4; ++p)
        if (t0 + p < S1) op[p] = fmaxf(acc[cc][p], 0.f);
    }
  }
}

// h2: 4 pixels x 8 co per thread. float4 row-segment loads.
__global__ __launch_bounds__(256) void k_conv2(const float* __restrict__ h1e,
    const float* __restrict__ w2, const float* __restrict__ b2_, float* __restrict__ h2) {
  int v0 = threadIdx.x * 4;                  // 0..252
  int u = blockIdx.y * 4 + threadIdx.y;
  int zb = blockIdx.z;                       // n*2 + g
  int n = zb >> 1, cog = (zb & 1) * 8;
  if (u >= S2) return;
  float acc[8][4];
#pragma unroll
  for (int cc = 0; cc < 8; ++cc) {
    float b = b2_[cog + cc];
#pragma unroll
    for (int p = 0; p < 4; ++p) acc[cc][p] = b;
  }
  const float* hn = h1e + (size_t)n * 8 * S1S1;
  for (int ci = 0; ci < 8; ++ci) {
    const float* hc = hn + ci * S1S1;
#pragma unroll
    for (int ky = 0; ky < 3; ++ky) {
      const float* hr = hc + (u + ky) * S1 + v0;
      float4 r4 = *(const float4*)hr;
      float rr[6] = {r4.x, r4.y, r4.z, r4.w, hr[4], hr[5]};
#pragma unroll
      for (int cc = 0; cc < 8; ++cc) {
        const float* w = w2 + (cog + cc) * 72 + ci * 9 + ky * 3;
        float w0 = w[0], w1 = w[1], w2v = w[2];
#pragma unroll
        for (int p = 0; p < 4; ++p)
          acc[cc][p] = fmaf(rr[p], w0, fmaf(rr[p + 1], w1, fmaf(rr[p + 2], w2v, acc[cc][p])));
      }
    }
  }
#pragma unroll
  for (int cc = 0; cc < 8; ++cc) {
    float* op = h2 + ((size_t)(n * 16 + cog + cc) * S2 + u) * S2 + v0;
    if (v0 + 3 < S2) {
      *(float4*)op = make_float4(fmaxf(acc[cc][0], 0.f), fmaxf(acc[cc][1], 0.f),
                                 fmaxf(acc[cc][2], 0.f), fmaxf(acc[cc][3], 0.f));
    } else {
#pragma unroll
      for (int p = 0; p < 4; ++p)
        if (v0 + p < S2) op[p] = fmaxf(acc[cc][p], 0.f);
    }
  }
}

// h3core: 4 pixels x 8 co per thread. float4 row-segment loads.
__global__ __launch_bounds__(256) void k_deconv3(const float* __restrict__ h2,
    const float* __restrict__ w3, const float* __restrict__ b3_, float* __restrict__ h3c) {
  int r0 = threadIdx.x * 4;                  // 0..252
  int q = blockIdx.y * 4 + threadIdx.y;
  int n = blockIdx.z;
  if (q >= S1) return;
  float acc[8][4];
#pragma unroll
  for (int cc = 0; cc < 8; ++cc) {
    float b = b3_[cc];
#pragma unroll
    for (int p = 0; p < 4; ++p) acc[cc][p] = b;
  }
  const float* hn = h2 + (size_t)n * 16 * S2S2;
  bool inner = (r0 >= 4 && r0 <= 248);
  for (int ci = 0; ci < 16; ++ci) {
    const float* hc = hn + ci * S2S2;
#pragma unroll
    for (int jy = 0; jy < 3; ++jy) {
      int a = q - jy;
      if ((unsigned)a > 252u) continue;
      const float* hr = hc + a * S2 + (r0 - 2);
      float rr[6];
      if (inner) {
        float4 r4 = *(const float4*)hr;
        rr[0] = r4.x; rr[1] = r4.y; rr[2] = r4.z; rr[3] = r4.w;
        rr[4] = hr[4]; rr[5] = hr[5];
      } else {
#pragma unroll
        for (int q2 = 0; q2 < 6; ++q2) {
          int col = r0 - 2 + q2;
          rr[q2] = ((unsigned)col <= 252u) ? hr[q2] : 0.f;
        }
      }
#pragma unroll
      for (int cc = 0; cc < 8; ++cc) {
        const float* w = w3 + (cc * 16 + ci) * 9 + jy * 3;
        float w0 = w[0], w1 = w[1], w2v = w[2];
#pragma unroll
        for (int p = 0; p < 4; ++p)
          acc[cc][p] = fmaf(rr[p + 2], w0, fmaf(rr[p + 1], w1, fmaf(rr[p], w2v, acc[cc][p])));
      }
    }
  }
#pragma unroll
  for (int cc = 0; cc < 8; ++cc) {
    float* op = h3c + ((size_t)(n * 8 + cc) * S1 + q) * S1 + r0;
    if (r0 + 3 < S1) {
      *(float4*)op = make_float4(fmaxf(acc[cc][0], 0.f), fmaxf(acc[cc][1], 0.f),
                                 fmaxf(acc[cc][2], 0.f), fmaxf(acc[cc][3], 0.f));
    } else {
#pragma unroll
      for (int p = 0; p < 4; ++p)
        if (r0 + p < S1) op[p] = fmaxf(acc[cc][p], 0.f);
    }
  }
}

// General (border) per-element output value.
__device__ __forceinline__ float general_val(unsigned idx, const float* __restrict__ h3c,
    const float* __restrict__ w4, const float* __restrict__ b4_, const float* __restrict__ b3_) {
  unsigned z = idx / PLANE;
  unsigned rem = idx - z * PLANE;
  unsigned y = rem / 1021u;
  unsigned x = rem - y * 1021u;
  int co = z & 7;
  float acc = b4_[co];
  if ((y | x) & 1u) return acc;
  int py = y >> 1, px = x >> 1;
  const float* hn = h3c + (size_t)(z >> 3) * 8 * S1S1;
  const float* wp = w4 + co * 72;
  for (int ci = 0; ci < 8; ++ci) {
    float r3 = fmaxf(b3_[ci], 0.f);
    const float* hcc = hn + ci * S1S1;
#pragma unroll
    for (int jy = 0; jy < 3; ++jy) {
      int a = py - jy;
#pragma unroll
      for (int jx = 0; jx < 3; ++jx) {
        int b = px - jx;
        float h;
        if ((unsigned)a > 508u || (unsigned)b > 508u) h = 0.f;
        else if (((a | b) & 1) == 0) h = hcc[(a >> 1) * S1 + (b >> 1)];
        else h = r3;
        acc = fmaf(h, wp[ci * 9 + jy * 3 + jx], acc);
      }
    }
  }
  return acc;
}

// Out kernel v3: block = (row-pair ye/ye+1, n). Each thread computes ALL 8 co
// from ONE set of h3c loads (8x fetch reduction vs per-z blocks). Weights/R/b4
// staged in LDS (broadcast reads). Odd row: 8 constant row-stores per block.
// Even rows ye in [4,1016], t in [1,253]: cols 4t..4t+3 (pxa = 2t, always even).
__global__ __launch_bounds__(256) void k_out_all(const float* __restrict__ h3c,
    const float* __restrict__ b4_, const float* __restrict__ R,
    const float* __restrict__ WT, float* __restrict__ out) {
  __shared__ float wt_s[768];
  __shared__ float R_s[32];
  __shared__ float b4_s[8];
  int t = threadIdx.x;
  if (t < 192) *(float4*)(wt_s + 4 * t) = *(const float4*)(WT + 4 * t);
  if (t < 32) R_s[t] = R[t];
  if (t < 8) b4_s[t] = b4_[t];
  __syncthreads();

  int ye = blockIdx.x * 2;                   // 0..1020
  int n = blockIdx.y;                        // 0..7
  const float* hn = h3c + (size_t)n * 8 * S1S1;
  float* obase = out + (size_t)(n * 8) * PLANE + (size_t)ye * 1021u;

  // odd row ye+1: constants for all 8 co
  if (ye < 1020) {
#pragma unroll
    for (int co = 0; co < 8; ++co) {
      float b = b4_s[co];
      float* row = obase + (size_t)co * PLANE + 1021;
      if (t < 255) *(float4*)(row + 4 * t) = make_float4(b, b, b, b);
      else row[1020] = b;
    }
  }

  if (ye < 4 || ye > 1016) return;
  if (t == 0 || t >= 254) return;
  unsigned py = (unsigned)ye >> 1;           // 2..508
  int col0 = t - 1;
  if ((py & 1u) == 0) {
    unsigned i = py >> 1;                    // rows i-1, i of h3c
    const float* hp = hn + (i - 1) * S1 + col0;
    float m00[8], m01[8], m10[8], m11[8];
#pragma unroll
    for (int ci = 0; ci < 8; ++ci) {
      const float* p = hp + ci * S1S1;
      m00[ci] = p[0]; m01[ci] = p[1]; m10[ci] = p[S1]; m11[ci] = p[S1 + 1];
    }
#pragma unroll
    for (int co = 0; co < 8; ++co) {
      const float* wt = wt_s + co * 96;
      float vE = 0.f, vO = 0.f;
#pragma unroll
      for (int ci = 0; ci < 8; ++ci) {
        const float* ww = wt + ci * 12;
        vE = fmaf(m11[ci], ww[0], fmaf(m10[ci], ww[1], fmaf(m01[ci], ww[2], fmaf(m00[ci], ww[3], vE))));
        vO = fmaf(m11[ci], ww[4], fmaf(m01[ci], ww[5], vO));
      }
      float b = b4_s[co];
      float rE = b + R_s[co * 4 + 0] + vE;
      float rO = b + R_s[co * 4 + 1] + vO;
      *(float4*)(obase + (size_t)co * PLANE + 4 * t) = make_float4(rE, b, rO, b);
    }
  } else {
    unsigned a = py >> 1;                    // single row a of h3c
    const float* hp = hn + a * S1 + col0;
    float n0[8], n1[8];
#pragma unroll
    for (int ci = 0; ci < 8; ++ci) {
      const float* p = hp + ci * S1S1;
      n0[ci] = p[0]; n1[ci] = p[1];
    }
#pragma unroll
    for (int co = 0; co < 8; ++co) {
      const float* wt = wt_s + co * 96;
      float vE = 0.f, vO = 0.f;
#pragma unroll
      for (int ci = 0; ci < 8; ++ci) {
        const float* ww = wt + ci * 12;
        vE = fmaf(n1[ci], ww[6], fmaf(n0[ci], ww[7], vE));
        vO = fmaf(n1[ci], ww[8], vO);
      }
      float b = b4_s[co];
      float rE = b + R_s[co * 4 + 2] + vE;
      float rO = b + R_s[co * 4 + 3] + vO;
      *(float4*)(obase + (size_t)co * PLANE + 4 * t) = make_float4(rE, b, rO, b);
    }
  }
}

// Border kernel: even-row x-borders (x in {0..3} u {1016..1020}, ye=4..1016: 507 rows)
// and the 4 even border rows (y in {0,2,1018,1020}) in full. ~2% of output.
__global__ __launch_bounds__(256) void k_out_border(const float* __restrict__ h3c,
    const float* __restrict__ w4, const float* __restrict__ b4_,
    const float* __restrict__ b3_, float* __restrict__ out) {
  int z = blockIdx.y;
  unsigned y, x;
  if (blockIdx.x < 18) {                     // x-border: 507*9 = 4563 elements
    unsigned e = blockIdx.x * 256 + threadIdx.x;
    if (e >= 507u * 9u) return;
    unsigned r = e / 9u, c = e - r * 9u;
    y = 4u + 2u * r;
    x = (c < 4u) ? c : (1012u + c);          // c=4..8 -> 1016..1020
  } else {                                   // y-border rows: 4*1021 = 4084 elements
    unsigned e2 = (blockIdx.x - 18) * 256 + threadIdx.x;
    if (e2 >= 4u * 1021u) return;
    unsigned rr = e2 / 1021u;
    y = (rr < 2u) ? 2u * rr : (1014u + 2u * rr);   // 0,2,1018,1020
    x = e2 - rr * 1021u;
  }
  unsigned idx = (unsigned)z * PLANE + y * 1021u + x;
  out[idx] = general_val(idx, h3c, w4, b4_, b3_);
}

extern "C" void kernel_launch(void* const* d_in, const int* in_sizes, int n_in,
                              void* d_out, int out_size, void* d_ws, size_t ws_size,
                              hipStream_t stream) {
  const float* x   = (const float*)d_in[0];
  const float* w1  = (const float*)d_in[1];
  const float* b1_ = (const float*)d_in[2];
  const float* w2  = (const float*)d_in[3];
  const float* b2_ = (const float*)d_in[4];
  const float* w3  = (const float*)d_in[5];
  const float* b3_ = (const float*)d_in[6];
  const float* w4  = (const float*)d_in[7];
  const float* b4_ = (const float*)d_in[8];
  float* out = (float*)d_out;

  float* h1e = (float*)d_ws;
  float* h2  = h1e + (size_t)8 * 8 * S1S1;
  float* h3c = h2 + (size_t)8 * 16 * S2S2;
  float* R   = h3c + (size_t)8 * 8 * S1S1;
  float* WT  = R + 32;

  k_setup<<<1, 64, 0, stream>>>(w4, b3_, R, WT);
  k_conv1<<<dim3(1, 64, 8), dim3(64, 4), 0, stream>>>(x, w1, b1_, h1e);
  k_conv2<<<dim3(1, 64, 16), dim3(64, 4), 0, stream>>>(h1e, w2, b2_, h2);
  k_deconv3<<<dim3(1, 64, 8), dim3(64, 4), 0, stream>>>(h2, w3, b3_, h3c);
  k_out_all<<<dim3(511, 8), 256, 0, stream>>>(h3c, b4_, R, WT, out);
  k_out_border<<<dim3(34, 64), 256, 0, stream>>>(h3c, w4, b4_, b3_, out);
}